// Round 4
// baseline (204.614 us; speedup 1.0000x reference)
//
#include <hip/hip_runtime.h>
#include <hip/hip_bf16.h>
#include <cstdint>

#define D 128

typedef __attribute__((ext_vector_type(8))) short short8v;
typedef __attribute__((ext_vector_type(4))) float float4v;

__device__ __forceinline__ float bf2f(unsigned short u) {
    union { unsigned int i; float f; } x; x.i = ((unsigned int)u) << 16; return x.f;
}
__device__ __forceinline__ unsigned short f2bf(float f) {
    union { float f; unsigned int i; } x; x.f = f;
    unsigned int r = x.i + 0x7FFFu + ((x.i >> 16) & 1u);
    return (unsigned short)(r >> 16);
}

__device__ __forceinline__ void detect_body(const int* __restrict__ eidx, int nPairs,
                                            int* __restrict__ flag) {
    __shared__ int anyNZ;
    if (threadIdx.x == 0) anyNZ = 0;
    __syncthreads();
    int cnt = nPairs < 2048 ? nPairs : 2048;
    int local = 0;
    for (int i = threadIdx.x; i < cnt; i += 256)
        if (eidx[2 * i + 1] != 0) local = 1;
    if (local) anyNZ = 1;
    __syncthreads();
    if (threadIdx.x == 0) *flag = (anyNZ == 0) ? 1 : 0;
}

// blocks 0..127: W1 (fp32) -> Bc (bf16 [n=256][k=128]); block 128: int64 detect.
__global__ __launch_bounds__(256) void prep(
    const float* __restrict__ W1, unsigned short* __restrict__ Bc,
    const int* __restrict__ eidx, int nPairs, int* __restrict__ flag)
{
    if ((int)blockIdx.x < 128) {
        int i = blockIdx.x * 256 + threadIdx.x;
        int n = i >> 7, k = i & 127;
        Bc[i] = f2bf(W1[(size_t)((n < 128) ? k : k + 128) * D + (n & 127)]);
    } else {
        detect_body(eidx, nPairs, flag);
    }
}

__global__ __launch_bounds__(256) void detect_only(
    const int* __restrict__ eidx, int nPairs, int* __restrict__ flag)
{
    detect_body(eidx, nPairs, flag);
}

// U|V = X @ W1 via bf16 MFMA, swapped operands (mfma(B,A)).
// 16 nodes x 256 cols per block (wave w -> cols w*64..w*64+63).
// No LDS, no barriers: one X row-chunk load + cvt per lane, 16 MFMAs
// against L2-hot Bc fragments, direct 8B packed stores.
__global__ __launch_bounds__(256, 4) void uv_mfma(
    const float* __restrict__ X, const unsigned short* __restrict__ Bc,
    unsigned short* __restrict__ U, unsigned short* __restrict__ V, int nNodes)
{
    const int t = threadIdx.x;
    const int wave = t >> 6;
    const int l = t & 63;
    const int lr = l & 15;          // node lane
    const int lk = l >> 4;          // k-group lane
    const int node0 = blockIdx.x * 16;
    const int n0w = wave * 64;      // this wave's output-col base (0..255)

    const int row = node0 + lr;
    const int rowc = row < nNodes ? row : nNodes - 1;
    const float* xp = X + (size_t)rowc * D;

    // A-op fragments (X row): lane holds X[row][k = ks*32 + lk*8 + j], bf16
    short8v af[4];
#pragma unroll
    for (int ks = 0; ks < 4; ++ks) {
        float4 x0 = *reinterpret_cast<const float4*>(xp + ks * 32 + lk * 8);
        float4 x1 = *reinterpret_cast<const float4*>(xp + ks * 32 + lk * 8 + 4);
        short8v a;
        a[0] = (short)f2bf(x0.x); a[1] = (short)f2bf(x0.y);
        a[2] = (short)f2bf(x0.z); a[3] = (short)f2bf(x0.w);
        a[4] = (short)f2bf(x1.x); a[5] = (short)f2bf(x1.y);
        a[6] = (short)f2bf(x1.z); a[7] = (short)f2bf(x1.w);
        af[ks] = a;
    }

    // D[wcol][node]: lane holds node=lr, wcols n0w + nt*16 + lk*4 + (0..3)
    float4v acc[4];
#pragma unroll
    for (int nt = 0; nt < 4; ++nt) {
        acc[nt] = (float4v){0.f, 0.f, 0.f, 0.f};
#pragma unroll
        for (int ks = 0; ks < 4; ++ks) {
            short8v b = *reinterpret_cast<const short8v*>(
                Bc + (size_t)(n0w + nt * 16 + lr) * D + ks * 32 + lk * 8);
            acc[nt] = __builtin_amdgcn_mfma_f32_16x16x32_bf16(b, af[ks], acc[nt], 0, 0, 0);
        }
    }

    if (row < nNodes) {
        unsigned short* base = (n0w < 128 ? U : V) + (size_t)row * D + (n0w & 127);
#pragma unroll
        for (int nt = 0; nt < 4; ++nt) {
            ushort4 o;
            o.x = f2bf(acc[nt][0]); o.y = f2bf(acc[nt][1]);
            o.z = f2bf(acc[nt][2]); o.w = f2bf(acc[nt][3]);
            *reinterpret_cast<ushort4*>(base + nt * 16 + lk * 4) = o;
        }
    }
}

// One edge per 16 lanes (8 dims/lane, 16B gathers), 4 edges per group.
__global__ __launch_bounds__(256) void edge_attn(
    const int* __restrict__ eidx, const unsigned short* __restrict__ U,
    const unsigned short* __restrict__ V, const float* __restrict__ b1,
    const float* __restrict__ W2, const float* __restrict__ b2,
    const int* __restrict__ i64flag, float* __restrict__ out,
    int nEdges, int nNodes)
{
    const int t = threadIdx.x;
    const int g = t >> 4;
    const int lane = t & 15;
    const int ebase = (blockIdx.x * 16 + g) * 4;
    if (ebase >= nEdges) return;
    const int is64 = *i64flag;
    const bool vec4 = ((nEdges & 3) == 0);

    int si[4], di[4];
    if (vec4) {
        if (!is64) {
            int4 s4 = *reinterpret_cast<const int4*>(eidx + ebase);
            int4 d4 = *reinterpret_cast<const int4*>(eidx + nEdges + ebase);
            si[0] = s4.x; si[1] = s4.y; si[2] = s4.z; si[3] = s4.w;
            di[0] = d4.x; di[1] = d4.y; di[2] = d4.z; di[3] = d4.w;
        } else {
            int4 a = *reinterpret_cast<const int4*>(eidx + 2 * (size_t)ebase);
            int4 b = *reinterpret_cast<const int4*>(eidx + 2 * (size_t)ebase + 4);
            int4 c = *reinterpret_cast<const int4*>(eidx + 2 * ((size_t)nEdges + ebase));
            int4 d = *reinterpret_cast<const int4*>(eidx + 2 * ((size_t)nEdges + ebase) + 4);
            si[0] = a.x; si[1] = a.z; si[2] = b.x; si[3] = b.z;
            di[0] = c.x; di[1] = c.z; di[2] = d.x; di[3] = d.z;
        }
    } else {
#pragma unroll
        for (int i = 0; i < 4; ++i) {
            int e = ebase + i; if (e >= nEdges) e = nEdges - 1;
            size_t sOff = is64 ? (size_t)2 * e : (size_t)e;
            size_t dOff = is64 ? (size_t)2 * ((size_t)nEdges + e) : (size_t)nEdges + e;
            si[i] = eidx[sOff];
            di[i] = eidx[dOff];
        }
    }
#pragma unroll
    for (int i = 0; i < 4; ++i) {
        si[i] = min(max(si[i], 0), nNodes - 1);
        di[i] = min(max(di[i], 0), nNodes - 1);
    }
    uint4 u[4], v[4];
#pragma unroll
    for (int i = 0; i < 4; ++i)
        u[i] = *reinterpret_cast<const uint4*>(U + (size_t)si[i] * D + lane * 8);
#pragma unroll
    for (int i = 0; i < 4; ++i)
        v[i] = *reinterpret_cast<const uint4*>(V + (size_t)di[i] * D + lane * 8);

    float4 b1a = *reinterpret_cast<const float4*>(b1 + lane * 8);
    float4 b1b = *reinterpret_cast<const float4*>(b1 + lane * 8 + 4);
    float4 w0 = *reinterpret_cast<const float4*>(W2 + lane * 16);
    float4 w1 = *reinterpret_cast<const float4*>(W2 + lane * 16 + 4);
    float4 w2 = *reinterpret_cast<const float4*>(W2 + lane * 16 + 8);
    float4 w3 = *reinterpret_cast<const float4*>(W2 + lane * 16 + 12);
    const float bb0 = b2[0], bb1 = b2[1];

#pragma unroll
    for (int i = 0; i < 4; ++i) {
        const unsigned short* up = reinterpret_cast<const unsigned short*>(&u[i]);
        const unsigned short* vp = reinterpret_cast<const unsigned short*>(&v[i]);
        const float bv[8] = {b1a.x, b1a.y, b1a.z, b1a.w, b1b.x, b1b.y, b1b.z, b1b.w};
        const float wc[16] = {w0.x, w0.y, w0.z, w0.w, w1.x, w1.y, w1.z, w1.w,
                              w2.x, w2.y, w2.z, w2.w, w3.x, w3.y, w3.z, w3.w};
        float s0 = 0.f, s1 = 0.f;
#pragma unroll
        for (int j = 0; j < 8; ++j) {
            float h = fmaxf(bf2f(up[j]) + bf2f(vp[j]) + bv[j], 0.f);
            s0 += h * wc[2 * j];
            s1 += h * wc[2 * j + 1];
        }
#pragma unroll
        for (int m = 8; m; m >>= 1) {
            s0 += __shfl_xor(s0, m);
            s1 += __shfl_xor(s1, m);
        }
        if (lane == 0 && ebase + i < nEdges) {
            const int e = ebase + i;
            float a0 = s0 + bb0, a1 = s1 + bb1;
            float mx = fmaxf(a0, a1);
            float e0 = __expf(a0 - mx), e1 = __expf(a1 - mx);
            float r = 1.f / (e0 + e1);
            out[e] = e0 * r;
            out[(size_t)nEdges + e] = e1 * r;
        }
    }
}

// Fallback if workspace is too small: compute h directly per edge.
__global__ __launch_bounds__(256) void edge_attn_direct(
    const int* __restrict__ eidx, const float* __restrict__ X,
    const float* __restrict__ W1, const float* __restrict__ b1,
    const float* __restrict__ W2, const float* __restrict__ b2,
    const int* __restrict__ i64flag, float* __restrict__ out,
    int nEdges, int nNodes)
{
    const int t = threadIdx.x;
    const int lane = t & 31;
    const int e = blockIdx.x * 8 + (t >> 5);
    if (e >= nEdges) return;
    const int is64 = i64flag ? *i64flag : 0;
    size_t sOff = is64 ? (size_t)2 * e : (size_t)e;
    size_t dOff = is64 ? (size_t)2 * ((size_t)nEdges + e) : (size_t)nEdges + e;
    int si = min(max(eidx[sOff], 0), nNodes - 1);
    int di = min(max(eidx[dOff], 0), nNodes - 1);

    const int j0 = lane * 4;
    float4 bv = *reinterpret_cast<const float4*>(b1 + j0);
    float a0 = bv.x, a1 = bv.y, a2 = bv.z, a3 = bv.w;
    const float* xs = X + (size_t)si * D;
    const float* xd = X + (size_t)di * D;
    for (int k = 0; k < 128; ++k) {
        float s = xs[k];
        float4 w = *reinterpret_cast<const float4*>(W1 + (size_t)k * D + j0);
        a0 += s * w.x; a1 += s * w.y; a2 += s * w.z; a3 += s * w.w;
        float d = xd[k];
        float4 w2r = *reinterpret_cast<const float4*>(W1 + (size_t)(k + 128) * D + j0);
        a0 += d * w2r.x; a1 += d * w2r.y; a2 += d * w2r.z; a3 += d * w2r.w;
    }
    a0 = fmaxf(a0, 0.f); a1 = fmaxf(a1, 0.f); a2 = fmaxf(a2, 0.f); a3 = fmaxf(a3, 0.f);
    float4 wa = *reinterpret_cast<const float4*>(W2 + j0 * 2);
    float4 wb = *reinterpret_cast<const float4*>(W2 + j0 * 2 + 4);
    float s0 = a0 * wa.x + a1 * wa.z + a2 * wb.x + a3 * wb.z;
    float s1 = a0 * wa.y + a1 * wa.w + a2 * wb.y + a3 * wb.w;
#pragma unroll
    for (int m = 16; m; m >>= 1) {
        s0 += __shfl_xor(s0, m);
        s1 += __shfl_xor(s1, m);
    }
    if (lane == 0) {
        s0 += b2[0]; s1 += b2[1];
        float mx = fmaxf(s0, s1);
        float e0 = __expf(s0 - mx), e1 = __expf(s1 - mx);
        float r = 1.f / (e0 + e1);
        out[e] = e0 * r;
        out[(size_t)nEdges + e] = e1 * r;
    }
}

extern "C" void kernel_launch(void* const* d_in, const int* in_sizes, int n_in,
                              void* d_out, int out_size, void* d_ws, size_t ws_size,
                              hipStream_t stream)
{
    const float* X   = (const float*)d_in[0];
    const int*   eix = (const int*)d_in[1];
    const float* W1  = (const float*)d_in[2];
    const float* b1  = (const float*)d_in[3];
    const float* W2  = (const float*)d_in[4];
    const float* b2  = (const float*)d_in[5];
    float* out = (float*)d_out;

    const int nNodes = in_sizes[0] / D;
    const int nEdges = in_sizes[1] / 2;
    const size_t uvElems = (size_t)nNodes * D;
    const size_t uvBytes = uvElems * sizeof(unsigned short);
    const size_t bcBytes = 256 * D * sizeof(unsigned short);   // 64 KB

    if (ws_size >= bcBytes + 2 * uvBytes + 16) {
        unsigned short* Bc = (unsigned short*)d_ws;
        unsigned short* U  = (unsigned short*)((char*)d_ws + bcBytes);
        unsigned short* V  = U + uvElems;
        int* flag = (int*)((char*)d_ws + bcBytes + 2 * uvBytes);
        prep<<<129, 256, 0, stream>>>(W1, Bc, eix, nEdges, flag);
        uv_mfma<<<(nNodes + 15) / 16, 256, 0, stream>>>(X, Bc, U, V, nNodes);
        const int nbEdge = (nEdges + 63) / 64;
        edge_attn<<<nbEdge, 256, 0, stream>>>(eix, U, V, b1, W2, b2, flag, out, nEdges, nNodes);
    } else {
        int* flag = (ws_size >= 4) ? (int*)d_ws : nullptr;
        if (flag) detect_only<<<1, 256, 0, stream>>>(eix, nEdges, flag);
        const int nbEdge = (nEdges + 7) / 8;
        edge_attn_direct<<<nbEdge, 256, 0, stream>>>(eix, X, W1, b1, W2, b2, flag, out, nEdges, nNodes);
    }
}

// Round 5
// 181.494 us; speedup vs baseline: 1.1274x; 1.1274x over previous
//
#include <hip/hip_runtime.h>
#include <hip/hip_bf16.h>
#include <cstdint>

#define D 128

typedef __attribute__((ext_vector_type(8))) short short8v;
typedef __attribute__((ext_vector_type(4))) float float4v;

__device__ __forceinline__ float bf2f(unsigned short u) {
    union { unsigned int i; float f; } x; x.i = ((unsigned int)u) << 16; return x.f;
}
__device__ __forceinline__ unsigned short f2bf(float f) {
    union { float f; unsigned int i; } x; x.f = f;
    unsigned int r = x.i + 0x7FFFu + ((x.i >> 16) & 1u);
    return (unsigned short)(r >> 16);
}

__device__ __forceinline__ void detect_body(const int* __restrict__ eidx, int nPairs,
                                            int* __restrict__ flag) {
    __shared__ int anyNZ;
    if (threadIdx.x == 0) anyNZ = 0;
    __syncthreads();
    int cnt = nPairs < 2048 ? nPairs : 2048;
    int local = 0;
    for (int i = threadIdx.x; i < cnt; i += 256)
        if (eidx[2 * i + 1] != 0) local = 1;
    if (local) anyNZ = 1;
    __syncthreads();
    if (threadIdx.x == 0) *flag = (anyNZ == 0) ? 1 : 0;
}

// blocks 0..127: W1 (fp32) -> Bc (bf16 [n=256][k=128]); block 128: int64 detect.
__global__ __launch_bounds__(256) void prep(
    const float* __restrict__ W1, unsigned short* __restrict__ Bc,
    const int* __restrict__ eidx, int nPairs, int* __restrict__ flag)
{
    if ((int)blockIdx.x < 128) {
        int i = blockIdx.x * 256 + threadIdx.x;
        int n = i >> 7, k = i & 127;
        Bc[i] = f2bf(W1[(size_t)((n < 128) ? k : k + 128) * D + (n & 127)]);
    } else {
        detect_body(eidx, nPairs, flag);
    }
}

__global__ __launch_bounds__(256) void detect_only(
    const int* __restrict__ eidx, int nPairs, int* __restrict__ flag)
{
    detect_body(eidx, nPairs, flag);
}

// U|V = X @ W1 via bf16 MFMA, swapped operands (mfma(B,A)).
// 64 nodes x 256 cols per block (wave w -> cols w*64..63), 4 mt-tiles of 16
// nodes. B-fragments hoisted once per wave (64 VGPRs); X for tile mt+1
// prefetched while tile mt runs cvt+MFMA. No LDS, no barriers; direct 8B
// packed stores (proven cost-free in r4).
__global__ __launch_bounds__(256, 3) void uv_mfma(
    const float* __restrict__ X, const unsigned short* __restrict__ Bc,
    unsigned short* __restrict__ U, unsigned short* __restrict__ V, int nNodes)
{
    const int t = threadIdx.x;
    const int wave = t >> 6;
    const int l = t & 63;
    const int lr = l & 15;          // node lane
    const int lk = l >> 4;          // k-group lane
    const int n0w = wave * 64;      // this wave's output-col base (0..255)

    // hoisted B fragments: lane holds Bc[col = n0w+nt*16+lr][k = ks*32+lk*8+j]
    short8v bf[4][4];
#pragma unroll
    for (int nt = 0; nt < 4; ++nt)
#pragma unroll
        for (int ks = 0; ks < 4; ++ks)
            bf[nt][ks] = *reinterpret_cast<const short8v*>(
                Bc + (size_t)(n0w + nt * 16 + lr) * D + ks * 32 + lk * 8);

    int row = blockIdx.x * 64 + lr;
    // prologue: raw X for tile 0
    float4 xr[8];
    {
        const float* xp = X + (size_t)min(row, nNodes - 1) * D + lk * 8;
#pragma unroll
        for (int ks = 0; ks < 4; ++ks) {
            xr[2 * ks]     = *reinterpret_cast<const float4*>(xp + ks * 32);
            xr[2 * ks + 1] = *reinterpret_cast<const float4*>(xp + ks * 32 + 4);
        }
    }

#pragma unroll
    for (int mt = 0; mt < 4; ++mt) {
        // convert current tile to bf16 fragments
        short8v af[4];
#pragma unroll
        for (int ks = 0; ks < 4; ++ks) {
            const float4 x0 = xr[2 * ks], x1 = xr[2 * ks + 1];
            short8v a;
            a[0] = (short)f2bf(x0.x); a[1] = (short)f2bf(x0.y);
            a[2] = (short)f2bf(x0.z); a[3] = (short)f2bf(x0.w);
            a[4] = (short)f2bf(x1.x); a[5] = (short)f2bf(x1.y);
            a[6] = (short)f2bf(x1.z); a[7] = (short)f2bf(x1.w);
            af[ks] = a;
        }
        // prefetch next tile's raw X (latency hides under MFMAs below)
        if (mt < 3) {
            const float* np = X + (size_t)min(row + 16, nNodes - 1) * D + lk * 8;
#pragma unroll
            for (int ks = 0; ks < 4; ++ks) {
                xr[2 * ks]     = *reinterpret_cast<const float4*>(np + ks * 32);
                xr[2 * ks + 1] = *reinterpret_cast<const float4*>(np + ks * 32 + 4);
            }
        }
        // D[wcol][node]: lane holds node=lr, wcols n0w + nt*16 + lk*4 + (0..3)
        float4v acc[4];
#pragma unroll
        for (int nt = 0; nt < 4; ++nt) {
            acc[nt] = (float4v){0.f, 0.f, 0.f, 0.f};
#pragma unroll
            for (int ks = 0; ks < 4; ++ks)
                acc[nt] = __builtin_amdgcn_mfma_f32_16x16x32_bf16(
                    bf[nt][ks], af[ks], acc[nt], 0, 0, 0);
        }
        if (row < nNodes) {
            unsigned short* base = (n0w < 128 ? U : V) + (size_t)row * D + (n0w & 127);
#pragma unroll
            for (int nt = 0; nt < 4; ++nt) {
                ushort4 o;
                o.x = f2bf(acc[nt][0]); o.y = f2bf(acc[nt][1]);
                o.z = f2bf(acc[nt][2]); o.w = f2bf(acc[nt][3]);
                *reinterpret_cast<ushort4*>(base + nt * 16 + lk * 4) = o;
            }
        }
        row += 16;
    }
}

// One edge per 16 lanes (8 dims/lane, 16B gathers), 8 edges per group:
// 16 outstanding gathers per wave before any compute.
__global__ __launch_bounds__(256, 4) void edge_attn(
    const int* __restrict__ eidx, const unsigned short* __restrict__ U,
    const unsigned short* __restrict__ V, const float* __restrict__ b1,
    const float* __restrict__ W2, const float* __restrict__ b2,
    const int* __restrict__ i64flag, float* __restrict__ out,
    int nEdges, int nNodes)
{
    const int t = threadIdx.x;
    const int g = t >> 4;
    const int lane = t & 15;
    const int ebase = (blockIdx.x * 16 + g) * 8;
    if (ebase >= nEdges) return;
    const int is64 = *i64flag;
    const bool vec = ((nEdges & 7) == 0);

    int si[8], di[8];
    if (vec) {
        if (!is64) {
            int4 a = *reinterpret_cast<const int4*>(eidx + ebase);
            int4 b = *reinterpret_cast<const int4*>(eidx + ebase + 4);
            int4 c = *reinterpret_cast<const int4*>(eidx + (size_t)nEdges + ebase);
            int4 d = *reinterpret_cast<const int4*>(eidx + (size_t)nEdges + ebase + 4);
            si[0] = a.x; si[1] = a.y; si[2] = a.z; si[3] = a.w;
            si[4] = b.x; si[5] = b.y; si[6] = b.z; si[7] = b.w;
            di[0] = c.x; di[1] = c.y; di[2] = c.z; di[3] = c.w;
            di[4] = d.x; di[5] = d.y; di[6] = d.z; di[7] = d.w;
        } else {
#pragma unroll
            for (int q = 0; q < 4; ++q) {
                int4 a = *reinterpret_cast<const int4*>(eidx + 2 * (size_t)ebase + 4 * q);
                si[2 * q] = a.x; si[2 * q + 1] = a.z;
                int4 c = *reinterpret_cast<const int4*>(
                    eidx + 2 * ((size_t)nEdges + ebase) + 4 * q);
                di[2 * q] = c.x; di[2 * q + 1] = c.z;
            }
        }
    } else {
#pragma unroll
        for (int i = 0; i < 8; ++i) {
            int e = ebase + i; if (e >= nEdges) e = nEdges - 1;
            size_t sOff = is64 ? (size_t)2 * e : (size_t)e;
            size_t dOff = is64 ? (size_t)2 * ((size_t)nEdges + e) : (size_t)nEdges + e;
            si[i] = eidx[sOff];
            di[i] = eidx[dOff];
        }
    }
#pragma unroll
    for (int i = 0; i < 8; ++i) {
        si[i] = min(max(si[i], 0), nNodes - 1);
        di[i] = min(max(di[i], 0), nNodes - 1);
    }
    // issue all 16 gathers before any compute
    uint4 u[8], v[8];
#pragma unroll
    for (int i = 0; i < 8; ++i)
        u[i] = *reinterpret_cast<const uint4*>(U + (size_t)si[i] * D + lane * 8);
#pragma unroll
    for (int i = 0; i < 8; ++i)
        v[i] = *reinterpret_cast<const uint4*>(V + (size_t)di[i] * D + lane * 8);

    float4 b1a = *reinterpret_cast<const float4*>(b1 + lane * 8);
    float4 b1b = *reinterpret_cast<const float4*>(b1 + lane * 8 + 4);
    float4 w0 = *reinterpret_cast<const float4*>(W2 + lane * 16);
    float4 w1 = *reinterpret_cast<const float4*>(W2 + lane * 16 + 4);
    float4 w2 = *reinterpret_cast<const float4*>(W2 + lane * 16 + 8);
    float4 w3 = *reinterpret_cast<const float4*>(W2 + lane * 16 + 12);
    const float bb0 = b2[0], bb1 = b2[1];
    const float bv[8] = {b1a.x, b1a.y, b1a.z, b1a.w, b1b.x, b1b.y, b1b.z, b1b.w};
    const float wc[16] = {w0.x, w0.y, w0.z, w0.w, w1.x, w1.y, w1.z, w1.w,
                          w2.x, w2.y, w2.z, w2.w, w3.x, w3.y, w3.z, w3.w};

#pragma unroll
    for (int i = 0; i < 8; ++i) {
        const unsigned short* up = reinterpret_cast<const unsigned short*>(&u[i]);
        const unsigned short* vp = reinterpret_cast<const unsigned short*>(&v[i]);
        float s0 = 0.f, s1 = 0.f;
#pragma unroll
        for (int j = 0; j < 8; ++j) {
            float h = fmaxf(bf2f(up[j]) + bf2f(vp[j]) + bv[j], 0.f);
            s0 += h * wc[2 * j];
            s1 += h * wc[2 * j + 1];
        }
#pragma unroll
        for (int m = 8; m; m >>= 1) {
            s0 += __shfl_xor(s0, m);
            s1 += __shfl_xor(s1, m);
        }
        if (lane == 0 && ebase + i < nEdges) {
            const int e = ebase + i;
            float a0 = s0 + bb0, a1 = s1 + bb1;
            float mx = fmaxf(a0, a1);
            float e0 = __expf(a0 - mx), e1 = __expf(a1 - mx);
            float r = 1.f / (e0 + e1);
            out[e] = e0 * r;
            out[(size_t)nEdges + e] = e1 * r;
        }
    }
}

// Fallback if workspace is too small: compute h directly per edge.
__global__ __launch_bounds__(256) void edge_attn_direct(
    const int* __restrict__ eidx, const float* __restrict__ X,
    const float* __restrict__ W1, const float* __restrict__ b1,
    const float* __restrict__ W2, const float* __restrict__ b2,
    const int* __restrict__ i64flag, float* __restrict__ out,
    int nEdges, int nNodes)
{
    const int t = threadIdx.x;
    const int lane = t & 31;
    const int e = blockIdx.x * 8 + (t >> 5);
    if (e >= nEdges) return;
    const int is64 = i64flag ? *i64flag : 0;
    size_t sOff = is64 ? (size_t)2 * e : (size_t)e;
    size_t dOff = is64 ? (size_t)2 * ((size_t)nEdges + e) : (size_t)nEdges + e;
    int si = min(max(eidx[sOff], 0), nNodes - 1);
    int di = min(max(eidx[dOff], 0), nNodes - 1);

    const int j0 = lane * 4;
    float4 bv = *reinterpret_cast<const float4*>(b1 + j0);
    float a0 = bv.x, a1 = bv.y, a2 = bv.z, a3 = bv.w;
    const float* xs = X + (size_t)si * D;
    const float* xd = X + (size_t)di * D;
    for (int k = 0; k < 128; ++k) {
        float s = xs[k];
        float4 w = *reinterpret_cast<const float4*>(W1 + (size_t)k * D + j0);
        a0 += s * w.x; a1 += s * w.y; a2 += s * w.z; a3 += s * w.w;
        float d = xd[k];
        float4 w2r = *reinterpret_cast<const float4*>(W1 + (size_t)(k + 128) * D + j0);
        a0 += d * w2r.x; a1 += d * w2r.y; a2 += d * w2r.z; a3 += d * w2r.w;
    }
    a0 = fmaxf(a0, 0.f); a1 = fmaxf(a1, 0.f); a2 = fmaxf(a2, 0.f); a3 = fmaxf(a3, 0.f);
    float4 wa = *reinterpret_cast<const float4*>(W2 + j0 * 2);
    float4 wb = *reinterpret_cast<const float4*>(W2 + j0 * 2 + 4);
    float s0 = a0 * wa.x + a1 * wa.z + a2 * wb.x + a3 * wb.z;
    float s1 = a0 * wa.y + a1 * wa.w + a2 * wb.y + a3 * wb.w;
#pragma unroll
    for (int m = 16; m; m >>= 1) {
        s0 += __shfl_xor(s0, m);
        s1 += __shfl_xor(s1, m);
    }
    if (lane == 0) {
        s0 += b2[0]; s1 += b2[1];
        float mx = fmaxf(s0, s1);
        float e0 = __expf(s0 - mx), e1 = __expf(s1 - mx);
        float r = 1.f / (e0 + e1);
        out[e] = e0 * r;
        out[(size_t)nEdges + e] = e1 * r;
    }
}

extern "C" void kernel_launch(void* const* d_in, const int* in_sizes, int n_in,
                              void* d_out, int out_size, void* d_ws, size_t ws_size,
                              hipStream_t stream)
{
    const float* X   = (const float*)d_in[0];
    const int*   eix = (const int*)d_in[1];
    const float* W1  = (const float*)d_in[2];
    const float* b1  = (const float*)d_in[3];
    const float* W2  = (const float*)d_in[4];
    const float* b2  = (const float*)d_in[5];
    float* out = (float*)d_out;

    const int nNodes = in_sizes[0] / D;
    const int nEdges = in_sizes[1] / 2;
    const size_t uvElems = (size_t)nNodes * D;
    const size_t uvBytes = uvElems * sizeof(unsigned short);
    const size_t bcBytes = 256 * D * sizeof(unsigned short);   // 64 KB

    if (ws_size >= bcBytes + 2 * uvBytes + 16) {
        unsigned short* Bc = (unsigned short*)d_ws;
        unsigned short* U  = (unsigned short*)((char*)d_ws + bcBytes);
        unsigned short* V  = U + uvElems;
        int* flag = (int*)((char*)d_ws + bcBytes + 2 * uvBytes);
        prep<<<129, 256, 0, stream>>>(W1, Bc, eix, nEdges, flag);
        uv_mfma<<<(nNodes + 63) / 64, 256, 0, stream>>>(X, Bc, U, V, nNodes);
        const int nbEdge = (nEdges + 127) / 128;
        edge_attn<<<nbEdge, 256, 0, stream>>>(eix, U, V, b1, W2, b2, flag, out, nEdges, nNodes);
    } else {
        int* flag = (ws_size >= 4) ? (int*)d_ws : nullptr;
        if (flag) detect_only<<<1, 256, 0, stream>>>(eix, nEdges, flag);
        const int nbEdge = (nEdges + 7) / 8;
        edge_attn_direct<<<nbEdge, 256, 0, stream>>>(eix, X, W1, b1, W2, b2, flag, out, nEdges, nNodes);
    }
}

// Round 6
// 176.323 us; speedup vs baseline: 1.1604x; 1.0293x over previous
//
#include <hip/hip_runtime.h>
#include <hip/hip_bf16.h>
#include <cstdint>

#define D 128

typedef __attribute__((ext_vector_type(8))) short short8v;
typedef __attribute__((ext_vector_type(4))) float float4v;

__device__ __forceinline__ float bf2f(unsigned short u) {
    union { unsigned int i; float f; } x; x.i = ((unsigned int)u) << 16; return x.f;
}
__device__ __forceinline__ unsigned short f2bf(float f) {
    union { float f; unsigned int i; } x; x.f = f;
    unsigned int r = x.i + 0x7FFFu + ((x.i >> 16) & 1u);
    return (unsigned short)(r >> 16);
}

__device__ __forceinline__ void detect_body(const int* __restrict__ eidx, int nPairs,
                                            int* __restrict__ flag) {
    __shared__ int anyNZ;
    if (threadIdx.x == 0) anyNZ = 0;
    __syncthreads();
    int cnt = nPairs < 2048 ? nPairs : 2048;
    int local = 0;
    for (int i = threadIdx.x; i < cnt; i += 256)
        if (eidx[2 * i + 1] != 0) local = 1;
    if (local) anyNZ = 1;
    __syncthreads();
    if (threadIdx.x == 0) *flag = (anyNZ == 0) ? 1 : 0;
}

// blocks 0..127: W1 (fp32) -> Bc (bf16 [n=256][k=128]);
// block 128: int64-layout detect;
// blocks 129..: X (fp32) -> Xb (bf16), 8 elems/thread, streaming.
__global__ __launch_bounds__(256) void prep(
    const float* __restrict__ X, const float* __restrict__ W1,
    unsigned short* __restrict__ Bc, unsigned short* __restrict__ Xb,
    const int* __restrict__ eidx, int nPairs, int* __restrict__ flag, int nChunks)
{
    const int b = blockIdx.x;
    if (b < 128) {
        int i = b * 256 + threadIdx.x;
        int n = i >> 7, k = i & 127;
        Bc[i] = f2bf(W1[(size_t)((n < 128) ? k : k + 128) * D + (n & 127)]);
    } else if (b == 128) {
        detect_body(eidx, nPairs, flag);
    } else {
        int c = (b - 129) * 256 + threadIdx.x;
        if (c < nChunks) {
            const float* p = X + (size_t)c * 8;
            float4 x0 = *reinterpret_cast<const float4*>(p);
            float4 x1 = *reinterpret_cast<const float4*>(p + 4);
            short8v o;
            o[0] = (short)f2bf(x0.x); o[1] = (short)f2bf(x0.y);
            o[2] = (short)f2bf(x0.z); o[3] = (short)f2bf(x0.w);
            o[4] = (short)f2bf(x1.x); o[5] = (short)f2bf(x1.y);
            o[6] = (short)f2bf(x1.z); o[7] = (short)f2bf(x1.w);
            *reinterpret_cast<short8v*>(Xb + (size_t)c * 8) = o;
        }
    }
}

// U|V = Xb @ W1 via bf16 MFMA, swapped operands (mfma(B,A)).
// 128 nodes x 256 cols per block (wave w -> cols w*64..w*64+63), 8 mt-tiles.
// B-fragments force-hoisted via asm (compiler cannot rematerialize); A loaded
// as ready-made bf16 fragments (no cvt in hot loop), depth-1 prefetched.
__global__ __launch_bounds__(256, 4) void uv_mfma(
    const unsigned short* __restrict__ Xb, const unsigned short* __restrict__ Bc,
    unsigned short* __restrict__ U, unsigned short* __restrict__ V, int nNodes)
{
    const int t = threadIdx.x;
    const int wave = t >> 6;
    const int l = t & 63;
    const int lr = l & 15;          // node lane / B-col lane
    const int lk = l >> 4;          // k-group lane
    const int n0w = wave * 64;      // this wave's output-col base (0..255)

    // hoisted B fragments: lane holds Bc[col = n0w+nt*16+lr][k = ks*32+lk*8+j]
    short8v bf[4][4];
#pragma unroll
    for (int nt = 0; nt < 4; ++nt)
#pragma unroll
        for (int ks = 0; ks < 4; ++ks)
            bf[nt][ks] = *reinterpret_cast<const short8v*>(
                Bc + (size_t)(n0w + nt * 16 + lr) * D + ks * 32 + lk * 8);
    // pin: values become asm outputs -> cannot be re-loaded from memory
#pragma unroll
    for (int nt = 0; nt < 4; ++nt)
#pragma unroll
        for (int ks = 0; ks < 4; ++ks)
            asm volatile("" : "+v"(bf[nt][ks]));

    int row = blockIdx.x * 128 + lr;
    const unsigned short* xbase = Xb + lk * 8;

    short8v aC[4], aN[4];
    {
        const unsigned short* p = xbase + (size_t)min(row, nNodes - 1) * D;
#pragma unroll
        for (int ks = 0; ks < 4; ++ks)
            aC[ks] = *reinterpret_cast<const short8v*>(p + ks * 32);
    }

#pragma unroll
    for (int mt = 0; mt < 8; ++mt) {
        if (mt < 7) {
            const unsigned short* p = xbase + (size_t)min(row + 16, nNodes - 1) * D;
#pragma unroll
            for (int ks = 0; ks < 4; ++ks)
                aN[ks] = *reinterpret_cast<const short8v*>(p + ks * 32);
        }
        // D[wcol][node]: lane holds node=lr, wcols n0w + nt*16 + lk*4 + (0..3)
        float4v acc[4];
#pragma unroll
        for (int nt = 0; nt < 4; ++nt) {
            acc[nt] = (float4v){0.f, 0.f, 0.f, 0.f};
#pragma unroll
            for (int ks = 0; ks < 4; ++ks)
                acc[nt] = __builtin_amdgcn_mfma_f32_16x16x32_bf16(
                    bf[nt][ks], aC[ks], acc[nt], 0, 0, 0);
        }
        if (row < nNodes) {
            unsigned short* base = (n0w < 128 ? U : V) + (size_t)row * D + (n0w & 127);
#pragma unroll
            for (int nt = 0; nt < 4; ++nt) {
                ushort4 o;
                o.x = f2bf(acc[nt][0]); o.y = f2bf(acc[nt][1]);
                o.z = f2bf(acc[nt][2]); o.w = f2bf(acc[nt][3]);
                *reinterpret_cast<ushort4*>(base + nt * 16 + lk * 4) = o;
            }
        }
        row += 16;
#pragma unroll
        for (int ks = 0; ks < 4; ++ks) aC[ks] = aN[ks];
    }
}

// Mid-tier fallback (ws fits U,V but not Xb): r5 kernel, fp32 X + in-kernel cvt.
__global__ __launch_bounds__(256, 3) void uv_mfma_f32(
    const float* __restrict__ X, const unsigned short* __restrict__ Bc,
    unsigned short* __restrict__ U, unsigned short* __restrict__ V, int nNodes)
{
    const int t = threadIdx.x;
    const int wave = t >> 6;
    const int l = t & 63;
    const int lr = l & 15;
    const int lk = l >> 4;
    const int n0w = wave * 64;

    short8v bf[4][4];
#pragma unroll
    for (int nt = 0; nt < 4; ++nt)
#pragma unroll
        for (int ks = 0; ks < 4; ++ks)
            bf[nt][ks] = *reinterpret_cast<const short8v*>(
                Bc + (size_t)(n0w + nt * 16 + lr) * D + ks * 32 + lk * 8);

    int row = blockIdx.x * 64 + lr;
    float4 xr[8];
    {
        const float* xp = X + (size_t)min(row, nNodes - 1) * D + lk * 8;
#pragma unroll
        for (int ks = 0; ks < 4; ++ks) {
            xr[2 * ks]     = *reinterpret_cast<const float4*>(xp + ks * 32);
            xr[2 * ks + 1] = *reinterpret_cast<const float4*>(xp + ks * 32 + 4);
        }
    }
#pragma unroll
    for (int mt = 0; mt < 4; ++mt) {
        short8v af[4];
#pragma unroll
        for (int ks = 0; ks < 4; ++ks) {
            const float4 x0 = xr[2 * ks], x1 = xr[2 * ks + 1];
            short8v a;
            a[0] = (short)f2bf(x0.x); a[1] = (short)f2bf(x0.y);
            a[2] = (short)f2bf(x0.z); a[3] = (short)f2bf(x0.w);
            a[4] = (short)f2bf(x1.x); a[5] = (short)f2bf(x1.y);
            a[6] = (short)f2bf(x1.z); a[7] = (short)f2bf(x1.w);
            af[ks] = a;
        }
        if (mt < 3) {
            const float* np = X + (size_t)min(row + 16, nNodes - 1) * D + lk * 8;
#pragma unroll
            for (int ks = 0; ks < 4; ++ks) {
                xr[2 * ks]     = *reinterpret_cast<const float4*>(np + ks * 32);
                xr[2 * ks + 1] = *reinterpret_cast<const float4*>(np + ks * 32 + 4);
            }
        }
        float4v acc[4];
#pragma unroll
        for (int nt = 0; nt < 4; ++nt) {
            acc[nt] = (float4v){0.f, 0.f, 0.f, 0.f};
#pragma unroll
            for (int ks = 0; ks < 4; ++ks)
                acc[nt] = __builtin_amdgcn_mfma_f32_16x16x32_bf16(
                    bf[nt][ks], af[ks], acc[nt], 0, 0, 0);
        }
        if (row < nNodes) {
            unsigned short* base = (n0w < 128 ? U : V) + (size_t)row * D + (n0w & 127);
#pragma unroll
            for (int nt = 0; nt < 4; ++nt) {
                ushort4 o;
                o.x = f2bf(acc[nt][0]); o.y = f2bf(acc[nt][1]);
                o.z = f2bf(acc[nt][2]); o.w = f2bf(acc[nt][3]);
                *reinterpret_cast<ushort4*>(base + nt * 16 + lk * 4) = o;
            }
        }
        row += 16;
    }
}

// One edge per 16 lanes (8 dims/lane, 16B gathers), 8 edges per group:
// 16 outstanding gathers per wave before any compute.
__global__ __launch_bounds__(256, 4) void edge_attn(
    const int* __restrict__ eidx, const unsigned short* __restrict__ U,
    const unsigned short* __restrict__ V, const float* __restrict__ b1,
    const float* __restrict__ W2, const float* __restrict__ b2,
    const int* __restrict__ i64flag, float* __restrict__ out,
    int nEdges, int nNodes)
{
    const int t = threadIdx.x;
    const int g = t >> 4;
    const int lane = t & 15;
    const int ebase = (blockIdx.x * 16 + g) * 8;
    if (ebase >= nEdges) return;
    const int is64 = *i64flag;
    const bool vec = ((nEdges & 7) == 0);

    int si[8], di[8];
    if (vec) {
        if (!is64) {
            int4 a = *reinterpret_cast<const int4*>(eidx + ebase);
            int4 b = *reinterpret_cast<const int4*>(eidx + ebase + 4);
            int4 c = *reinterpret_cast<const int4*>(eidx + (size_t)nEdges + ebase);
            int4 d = *reinterpret_cast<const int4*>(eidx + (size_t)nEdges + ebase + 4);
            si[0] = a.x; si[1] = a.y; si[2] = a.z; si[3] = a.w;
            si[4] = b.x; si[5] = b.y; si[6] = b.z; si[7] = b.w;
            di[0] = c.x; di[1] = c.y; di[2] = c.z; di[3] = c.w;
            di[4] = d.x; di[5] = d.y; di[6] = d.z; di[7] = d.w;
        } else {
#pragma unroll
            for (int q = 0; q < 4; ++q) {
                int4 a = *reinterpret_cast<const int4*>(eidx + 2 * (size_t)ebase + 4 * q);
                si[2 * q] = a.x; si[2 * q + 1] = a.z;
                int4 c = *reinterpret_cast<const int4*>(
                    eidx + 2 * ((size_t)nEdges + ebase) + 4 * q);
                di[2 * q] = c.x; di[2 * q + 1] = c.z;
            }
        }
    } else {
#pragma unroll
        for (int i = 0; i < 8; ++i) {
            int e = ebase + i; if (e >= nEdges) e = nEdges - 1;
            size_t sOff = is64 ? (size_t)2 * e : (size_t)e;
            size_t dOff = is64 ? (size_t)2 * ((size_t)nEdges + e) : (size_t)nEdges + e;
            si[i] = eidx[sOff];
            di[i] = eidx[dOff];
        }
    }
#pragma unroll
    for (int i = 0; i < 8; ++i) {
        si[i] = min(max(si[i], 0), nNodes - 1);
        di[i] = min(max(di[i], 0), nNodes - 1);
    }
    uint4 u[8], v[8];
#pragma unroll
    for (int i = 0; i < 8; ++i)
        u[i] = *reinterpret_cast<const uint4*>(U + (size_t)si[i] * D + lane * 8);
#pragma unroll
    for (int i = 0; i < 8; ++i)
        v[i] = *reinterpret_cast<const uint4*>(V + (size_t)di[i] * D + lane * 8);

    float4 b1a = *reinterpret_cast<const float4*>(b1 + lane * 8);
    float4 b1b = *reinterpret_cast<const float4*>(b1 + lane * 8 + 4);
    float4 w0 = *reinterpret_cast<const float4*>(W2 + lane * 16);
    float4 w1 = *reinterpret_cast<const float4*>(W2 + lane * 16 + 4);
    float4 w2 = *reinterpret_cast<const float4*>(W2 + lane * 16 + 8);
    float4 w3 = *reinterpret_cast<const float4*>(W2 + lane * 16 + 12);
    const float bb0 = b2[0], bb1 = b2[1];
    const float bv[8] = {b1a.x, b1a.y, b1a.z, b1a.w, b1b.x, b1b.y, b1b.z, b1b.w};
    const float wc[16] = {w0.x, w0.y, w0.z, w0.w, w1.x, w1.y, w1.z, w1.w,
                          w2.x, w2.y, w2.z, w2.w, w3.x, w3.y, w3.z, w3.w};

#pragma unroll
    for (int i = 0; i < 8; ++i) {
        const unsigned short* up = reinterpret_cast<const unsigned short*>(&u[i]);
        const unsigned short* vp = reinterpret_cast<const unsigned short*>(&v[i]);
        float s0 = 0.f, s1 = 0.f;
#pragma unroll
        for (int j = 0; j < 8; ++j) {
            float h = fmaxf(bf2f(up[j]) + bf2f(vp[j]) + bv[j], 0.f);
            s0 += h * wc[2 * j];
            s1 += h * wc[2 * j + 1];
        }
#pragma unroll
        for (int m = 8; m; m >>= 1) {
            s0 += __shfl_xor(s0, m);
            s1 += __shfl_xor(s1, m);
        }
        if (lane == 0 && ebase + i < nEdges) {
            const int e = ebase + i;
            float a0 = s0 + bb0, a1 = s1 + bb1;
            float mx = fmaxf(a0, a1);
            float e0 = __expf(a0 - mx), e1 = __expf(a1 - mx);
            float r = 1.f / (e0 + e1);
            out[e] = e0 * r;
            out[(size_t)nEdges + e] = e1 * r;
        }
    }
}

// Last-resort fallback: compute h directly per edge.
__global__ __launch_bounds__(256) void detect_only(
    const int* __restrict__ eidx, int nPairs, int* __restrict__ flag)
{
    detect_body(eidx, nPairs, flag);
}

__global__ __launch_bounds__(256) void edge_attn_direct(
    const int* __restrict__ eidx, const float* __restrict__ X,
    const float* __restrict__ W1, const float* __restrict__ b1,
    const float* __restrict__ W2, const float* __restrict__ b2,
    const int* __restrict__ i64flag, float* __restrict__ out,
    int nEdges, int nNodes)
{
    const int t = threadIdx.x;
    const int lane = t & 31;
    const int e = blockIdx.x * 8 + (t >> 5);
    if (e >= nEdges) return;
    const int is64 = i64flag ? *i64flag : 0;
    size_t sOff = is64 ? (size_t)2 * e : (size_t)e;
    size_t dOff = is64 ? (size_t)2 * ((size_t)nEdges + e) : (size_t)nEdges + e;
    int si = min(max(eidx[sOff], 0), nNodes - 1);
    int di = min(max(eidx[dOff], 0), nNodes - 1);

    const int j0 = lane * 4;
    float4 bv = *reinterpret_cast<const float4*>(b1 + j0);
    float a0 = bv.x, a1 = bv.y, a2 = bv.z, a3 = bv.w;
    const float* xs = X + (size_t)si * D;
    const float* xd = X + (size_t)di * D;
    for (int k = 0; k < 128; ++k) {
        float s = xs[k];
        float4 w = *reinterpret_cast<const float4*>(W1 + (size_t)k * D + j0);
        a0 += s * w.x; a1 += s * w.y; a2 += s * w.z; a3 += s * w.w;
        float d = xd[k];
        float4 w2r = *reinterpret_cast<const float4*>(W1 + (size_t)(k + 128) * D + j0);
        a0 += d * w2r.x; a1 += d * w2r.y; a2 += d * w2r.z; a3 += d * w2r.w;
    }
    a0 = fmaxf(a0, 0.f); a1 = fmaxf(a1, 0.f); a2 = fmaxf(a2, 0.f); a3 = fmaxf(a3, 0.f);
    float4 wa = *reinterpret_cast<const float4*>(W2 + j0 * 2);
    float4 wb = *reinterpret_cast<const float4*>(W2 + j0 * 2 + 4);
    float s0 = a0 * wa.x + a1 * wa.z + a2 * wb.x + a3 * wb.z;
    float s1 = a0 * wa.y + a1 * wa.w + a2 * wb.y + a3 * wb.w;
#pragma unroll
    for (int m = 16; m; m >>= 1) {
        s0 += __shfl_xor(s0, m);
        s1 += __shfl_xor(s1, m);
    }
    if (lane == 0) {
        s0 += b2[0]; s1 += b2[1];
        float mx = fmaxf(s0, s1);
        float e0 = __expf(s0 - mx), e1 = __expf(s1 - mx);
        float r = 1.f / (e0 + e1);
        out[e] = e0 * r;
        out[(size_t)nEdges + e] = e1 * r;
    }
}

extern "C" void kernel_launch(void* const* d_in, const int* in_sizes, int n_in,
                              void* d_out, int out_size, void* d_ws, size_t ws_size,
                              hipStream_t stream)
{
    const float* X   = (const float*)d_in[0];
    const int*   eix = (const int*)d_in[1];
    const float* W1  = (const float*)d_in[2];
    const float* b1  = (const float*)d_in[3];
    const float* W2  = (const float*)d_in[4];
    const float* b2  = (const float*)d_in[5];
    float* out = (float*)d_out;

    const int nNodes = in_sizes[0] / D;
    const int nEdges = in_sizes[1] / 2;
    const size_t uvElems = (size_t)nNodes * D;
    const size_t uvBytes = uvElems * sizeof(unsigned short);
    const size_t bcBytes = 256 * D * sizeof(unsigned short);   // 64 KB
    const size_t xbBytes = uvElems * sizeof(unsigned short);
    const int nbEdge8 = (nEdges + 127) / 128;

    if (ws_size >= bcBytes + xbBytes + 2 * uvBytes + 16) {
        // tier 1: Bc | Xb | U | V | flag
        unsigned short* Bc = (unsigned short*)d_ws;
        unsigned short* Xb = (unsigned short*)((char*)d_ws + bcBytes);
        unsigned short* U  = (unsigned short*)((char*)d_ws + bcBytes + xbBytes);
        unsigned short* V  = U + uvElems;
        int* flag = (int*)((char*)d_ws + bcBytes + xbBytes + 2 * uvBytes);
        const int nChunks = (int)(uvElems / 8);
        prep<<<129 + (nChunks + 255) / 256, 256, 0, stream>>>(
            X, W1, Bc, Xb, eix, nEdges, flag, nChunks);
        uv_mfma<<<(nNodes + 127) / 128, 256, 0, stream>>>(Xb, Bc, U, V, nNodes);
        edge_attn<<<nbEdge8, 256, 0, stream>>>(eix, U, V, b1, W2, b2, flag, out, nEdges, nNodes);
    } else if (ws_size >= bcBytes + 2 * uvBytes + 16) {
        // tier 2: Bc | U | V | flag  (r5 path)
        unsigned short* Bc = (unsigned short*)d_ws;
        unsigned short* U  = (unsigned short*)((char*)d_ws + bcBytes);
        unsigned short* V  = U + uvElems;
        int* flag = (int*)((char*)d_ws + bcBytes + 2 * uvBytes);
        prep<<<129, 256, 0, stream>>>(X, W1, Bc, nullptr, eix, nEdges, flag, 0);
        uv_mfma_f32<<<(nNodes + 63) / 64, 256, 0, stream>>>(X, Bc, U, V, nNodes);
        edge_attn<<<nbEdge8, 256, 0, stream>>>(eix, U, V, b1, W2, b2, flag, out, nEdges, nNodes);
    } else {
        int* flag = (ws_size >= 4) ? (int*)d_ws : nullptr;
        if (flag) detect_only<<<1, 256, 0, stream>>>(eix, nEdges, flag);
        const int nbEdge = (nEdges + 7) / 8;
        edge_attn_direct<<<nbEdge, 256, 0, stream>>>(eix, X, W1, b1, W2, b2, flag, out, nEdges, nNodes);
    }
}

// Round 7
// 173.812 us; speedup vs baseline: 1.1772x; 1.0144x over previous
//
#include <hip/hip_runtime.h>
#include <hip/hip_bf16.h>
#include <cstdint>

#define D 128

typedef __attribute__((ext_vector_type(8))) short short8v;
typedef __attribute__((ext_vector_type(4))) float float4v;
typedef __attribute__((ext_vector_type(4))) unsigned int uint4v;

__device__ __forceinline__ float bf2f(unsigned short u) {
    union { unsigned int i; float f; } x; x.i = ((unsigned int)u) << 16; return x.f;
}
__device__ __forceinline__ unsigned short f2bf(float f) {
    union { float f; unsigned int i; } x; x.f = f;
    unsigned int r = x.i + 0x7FFFu + ((x.i >> 16) & 1u);
    return (unsigned short)(r >> 16);
}

__device__ __forceinline__ void detect_body(const int* __restrict__ eidx, int nPairs,
                                            int* __restrict__ flag) {
    __shared__ int anyNZ;
    if (threadIdx.x == 0) anyNZ = 0;
    __syncthreads();
    int cnt = nPairs < 2048 ? nPairs : 2048;
    int local = 0;
    for (int i = threadIdx.x; i < cnt; i += 256)
        if (eidx[2 * i + 1] != 0) local = 1;
    if (local) anyNZ = 1;
    __syncthreads();
    if (threadIdx.x == 0) *flag = (anyNZ == 0) ? 1 : 0;
}

// blocks 0..127: W1 (fp32) -> Bc (bf16 [n=256][k=128]);
// block 128: int64-layout detect;
// blocks 129..: X (fp32) -> Xb (bf16), 8 elems/thread, streaming.
__global__ __launch_bounds__(256) void prep(
    const float* __restrict__ X, const float* __restrict__ W1,
    unsigned short* __restrict__ Bc, unsigned short* __restrict__ Xb,
    const int* __restrict__ eidx, int nPairs, int* __restrict__ flag, int nChunks)
{
    const int b = blockIdx.x;
    if (b < 128) {
        int i = b * 256 + threadIdx.x;
        int n = i >> 7, k = i & 127;
        Bc[i] = f2bf(W1[(size_t)((n < 128) ? k : k + 128) * D + (n & 127)]);
    } else if (b == 128) {
        detect_body(eidx, nPairs, flag);
    } else {
        int c = (b - 129) * 256 + threadIdx.x;
        if (c < nChunks) {
            const float* p = X + (size_t)c * 8;
            float4 x0 = *reinterpret_cast<const float4*>(p);
            float4 x1 = *reinterpret_cast<const float4*>(p + 4);
            short8v o;
            o[0] = (short)f2bf(x0.x); o[1] = (short)f2bf(x0.y);
            o[2] = (short)f2bf(x0.z); o[3] = (short)f2bf(x0.w);
            o[4] = (short)f2bf(x1.x); o[5] = (short)f2bf(x1.y);
            o[6] = (short)f2bf(x1.z); o[7] = (short)f2bf(x1.w);
            *reinterpret_cast<short8v*>(Xb + (size_t)c * 8) = o;
        }
    }
}

// U|V = Xb @ W1 via bf16 MFMA, swapped operands (mfma(B,A)).
// 128 nodes x 256 cols per block, 8 mt-tiles, B force-hoisted, A prefetched.
// b1 is folded into U here (fp32 add before bf16 pack) so the edge kernel
// computes h = relu(U' + V) with no bias load/add.
__global__ __launch_bounds__(256, 4) void uv_mfma(
    const unsigned short* __restrict__ Xb, const unsigned short* __restrict__ Bc,
    const float* __restrict__ b1,
    unsigned short* __restrict__ U, unsigned short* __restrict__ V, int nNodes)
{
    const int t = threadIdx.x;
    const int wave = t >> 6;
    const int l = t & 63;
    const int lr = l & 15;          // node lane / B-col lane
    const int lk = l >> 4;          // k-group lane
    const int n0w = wave * 64;      // this wave's output-col base (0..255)

    // hoisted B fragments: lane holds Bc[col = n0w+nt*16+lr][k = ks*32+lk*8+j]
    short8v bf[4][4];
#pragma unroll
    for (int nt = 0; nt < 4; ++nt)
#pragma unroll
        for (int ks = 0; ks < 4; ++ks)
            bf[nt][ks] = *reinterpret_cast<const short8v*>(
                Bc + (size_t)(n0w + nt * 16 + lr) * D + ks * 32 + lk * 8);
#pragma unroll
    for (int nt = 0; nt < 4; ++nt)
#pragma unroll
        for (int ks = 0; ks < 4; ++ks)
            asm volatile("" : "+v"(bf[nt][ks]));

    // bias for this lane's output cols (0 for V-columns)
    float4 bvv[4];
#pragma unroll
    for (int nt = 0; nt < 4; ++nt) {
        if (n0w < 128)
            bvv[nt] = *reinterpret_cast<const float4*>(b1 + n0w + nt * 16 + lk * 4);
        else
            bvv[nt] = make_float4(0.f, 0.f, 0.f, 0.f);
    }

    int row = blockIdx.x * 128 + lr;
    const unsigned short* xbase = Xb + lk * 8;

    short8v aC[4], aN[4];
    {
        const unsigned short* p = xbase + (size_t)min(row, nNodes - 1) * D;
#pragma unroll
        for (int ks = 0; ks < 4; ++ks)
            aC[ks] = *reinterpret_cast<const short8v*>(p + ks * 32);
    }

#pragma unroll
    for (int mt = 0; mt < 8; ++mt) {
        if (mt < 7) {
            const unsigned short* p = xbase + (size_t)min(row + 16, nNodes - 1) * D;
#pragma unroll
            for (int ks = 0; ks < 4; ++ks)
                aN[ks] = *reinterpret_cast<const short8v*>(p + ks * 32);
        }
        float4v acc[4];
#pragma unroll
        for (int nt = 0; nt < 4; ++nt) {
            acc[nt] = (float4v){0.f, 0.f, 0.f, 0.f};
#pragma unroll
            for (int ks = 0; ks < 4; ++ks)
                acc[nt] = __builtin_amdgcn_mfma_f32_16x16x32_bf16(
                    bf[nt][ks], aC[ks], acc[nt], 0, 0, 0);
        }
        if (row < nNodes) {
            unsigned short* base = (n0w < 128 ? U : V) + (size_t)row * D + (n0w & 127);
#pragma unroll
            for (int nt = 0; nt < 4; ++nt) {
                ushort4 o;
                o.x = f2bf(acc[nt][0] + bvv[nt].x);
                o.y = f2bf(acc[nt][1] + bvv[nt].y);
                o.z = f2bf(acc[nt][2] + bvv[nt].z);
                o.w = f2bf(acc[nt][3] + bvv[nt].w);
                *reinterpret_cast<ushort4*>(base + nt * 16 + lk * 4) = o;
            }
        }
        row += 16;
#pragma unroll
        for (int ks = 0; ks < 4; ++ks) aC[ks] = aN[ks];
    }
}

// Mid-tier fallback (ws fits U,V but not Xb): fp32 X + in-kernel cvt, b1 folded.
__global__ __launch_bounds__(256, 3) void uv_mfma_f32(
    const float* __restrict__ X, const unsigned short* __restrict__ Bc,
    const float* __restrict__ b1,
    unsigned short* __restrict__ U, unsigned short* __restrict__ V, int nNodes)
{
    const int t = threadIdx.x;
    const int wave = t >> 6;
    const int l = t & 63;
    const int lr = l & 15;
    const int lk = l >> 4;
    const int n0w = wave * 64;

    short8v bf[4][4];
#pragma unroll
    for (int nt = 0; nt < 4; ++nt)
#pragma unroll
        for (int ks = 0; ks < 4; ++ks)
            bf[nt][ks] = *reinterpret_cast<const short8v*>(
                Bc + (size_t)(n0w + nt * 16 + lr) * D + ks * 32 + lk * 8);

    float4 bvv[4];
#pragma unroll
    for (int nt = 0; nt < 4; ++nt) {
        if (n0w < 128)
            bvv[nt] = *reinterpret_cast<const float4*>(b1 + n0w + nt * 16 + lk * 4);
        else
            bvv[nt] = make_float4(0.f, 0.f, 0.f, 0.f);
    }

    int row = blockIdx.x * 64 + lr;
    float4 xr[8];
    {
        const float* xp = X + (size_t)min(row, nNodes - 1) * D + lk * 8;
#pragma unroll
        for (int ks = 0; ks < 4; ++ks) {
            xr[2 * ks]     = *reinterpret_cast<const float4*>(xp + ks * 32);
            xr[2 * ks + 1] = *reinterpret_cast<const float4*>(xp + ks * 32 + 4);
        }
    }
#pragma unroll
    for (int mt = 0; mt < 4; ++mt) {
        short8v af[4];
#pragma unroll
        for (int ks = 0; ks < 4; ++ks) {
            const float4 x0 = xr[2 * ks], x1 = xr[2 * ks + 1];
            short8v a;
            a[0] = (short)f2bf(x0.x); a[1] = (short)f2bf(x0.y);
            a[2] = (short)f2bf(x0.z); a[3] = (short)f2bf(x0.w);
            a[4] = (short)f2bf(x1.x); a[5] = (short)f2bf(x1.y);
            a[6] = (short)f2bf(x1.z); a[7] = (short)f2bf(x1.w);
            af[ks] = a;
        }
        if (mt < 3) {
            const float* np = X + (size_t)min(row + 16, nNodes - 1) * D + lk * 8;
#pragma unroll
            for (int ks = 0; ks < 4; ++ks) {
                xr[2 * ks]     = *reinterpret_cast<const float4*>(np + ks * 32);
                xr[2 * ks + 1] = *reinterpret_cast<const float4*>(np + ks * 32 + 4);
            }
        }
        float4v acc[4];
#pragma unroll
        for (int nt = 0; nt < 4; ++nt) {
            acc[nt] = (float4v){0.f, 0.f, 0.f, 0.f};
#pragma unroll
            for (int ks = 0; ks < 4; ++ks)
                acc[nt] = __builtin_amdgcn_mfma_f32_16x16x32_bf16(
                    bf[nt][ks], af[ks], acc[nt], 0, 0, 0);
        }
        if (row < nNodes) {
            unsigned short* base = (n0w < 128 ? U : V) + (size_t)row * D + (n0w & 127);
#pragma unroll
            for (int nt = 0; nt < 4; ++nt) {
                ushort4 o;
                o.x = f2bf(acc[nt][0] + bvv[nt].x);
                o.y = f2bf(acc[nt][1] + bvv[nt].y);
                o.z = f2bf(acc[nt][2] + bvv[nt].z);
                o.w = f2bf(acc[nt][3] + bvv[nt].w);
                *reinterpret_cast<ushort4*>(base + nt * 16 + lk * 4) = o;
            }
        }
        row += 16;
    }
}

// One edge per 16 lanes (8 dims/lane, 16B gathers), 8 edges per group.
// All 16 gathers force-pinned in flight; 32-bit byte-offset addressing;
// b1 pre-folded into U; softmax-over-2 as sigmoid.
__global__ __launch_bounds__(256, 4) void edge_attn(
    const int* __restrict__ eidx, const unsigned short* __restrict__ U,
    const unsigned short* __restrict__ V,
    const float* __restrict__ W2, const float* __restrict__ b2,
    const int* __restrict__ i64flag, float* __restrict__ out,
    int nEdges, int nNodes)
{
    const int t = threadIdx.x;
    const int g = t >> 4;
    const int lane = t & 15;
    const int ebase = (blockIdx.x * 16 + g) * 8;
    if (ebase >= nEdges) return;
    const int is64 = *i64flag;
    const bool vec = ((nEdges & 7) == 0);

    // hoisted uniforms (independent of gathers)
    float4 w0 = *reinterpret_cast<const float4*>(W2 + lane * 16);
    float4 w1 = *reinterpret_cast<const float4*>(W2 + lane * 16 + 4);
    float4 w2 = *reinterpret_cast<const float4*>(W2 + lane * 16 + 8);
    float4 w3 = *reinterpret_cast<const float4*>(W2 + lane * 16 + 12);
    const float bb0 = b2[0], bb1 = b2[1];

    int si[8], di[8];
    if (vec) {
        if (!is64) {
            int4 a = *reinterpret_cast<const int4*>(eidx + ebase);
            int4 b = *reinterpret_cast<const int4*>(eidx + ebase + 4);
            int4 c = *reinterpret_cast<const int4*>(eidx + (size_t)nEdges + ebase);
            int4 d = *reinterpret_cast<const int4*>(eidx + (size_t)nEdges + ebase + 4);
            si[0] = a.x; si[1] = a.y; si[2] = a.z; si[3] = a.w;
            si[4] = b.x; si[5] = b.y; si[6] = b.z; si[7] = b.w;
            di[0] = c.x; di[1] = c.y; di[2] = c.z; di[3] = c.w;
            di[4] = d.x; di[5] = d.y; di[6] = d.z; di[7] = d.w;
        } else {
#pragma unroll
            for (int q = 0; q < 4; ++q) {
                int4 a = *reinterpret_cast<const int4*>(eidx + 2 * (size_t)ebase + 4 * q);
                si[2 * q] = a.x; si[2 * q + 1] = a.z;
                int4 c = *reinterpret_cast<const int4*>(
                    eidx + 2 * ((size_t)nEdges + ebase) + 4 * q);
                di[2 * q] = c.x; di[2 * q + 1] = c.z;
            }
        }
    } else {
#pragma unroll
        for (int i = 0; i < 8; ++i) {
            int e = ebase + i; if (e >= nEdges) e = nEdges - 1;
            size_t sOff = is64 ? (size_t)2 * e : (size_t)e;
            size_t dOff = is64 ? (size_t)2 * ((size_t)nEdges + e) : (size_t)nEdges + e;
            si[i] = eidx[sOff];
            di[i] = eidx[dOff];
        }
    }
    const unsigned nmax = (unsigned)(nNodes - 1);
    const unsigned lane16 = (unsigned)lane << 4;
    // issue all 16 gathers (32-bit byte offsets), pin them in flight
    uint4v u[8], v[8];
#pragma unroll
    for (int i = 0; i < 8; ++i) {
        unsigned off = (min((unsigned)si[i], nmax) << 8) + lane16;
        u[i] = *reinterpret_cast<const uint4v*>((const char*)U + off);
    }
#pragma unroll
    for (int i = 0; i < 8; ++i) {
        unsigned off = (min((unsigned)di[i], nmax) << 8) + lane16;
        v[i] = *reinterpret_cast<const uint4v*>((const char*)V + off);
    }
#pragma unroll
    for (int i = 0; i < 8; ++i) {
        asm volatile("" : "+v"(u[i]));
        asm volatile("" : "+v"(v[i]));
    }

    const float wc[16] = {w0.x, w0.y, w0.z, w0.w, w1.x, w1.y, w1.z, w1.w,
                          w2.x, w2.y, w2.z, w2.w, w3.x, w3.y, w3.z, w3.w};

#pragma unroll
    for (int i = 0; i < 8; ++i) {
        const unsigned short* up = reinterpret_cast<const unsigned short*>(&u[i]);
        const unsigned short* vp = reinterpret_cast<const unsigned short*>(&v[i]);
        float s0 = 0.f, s1 = 0.f;
#pragma unroll
        for (int j = 0; j < 8; ++j) {
            float h = fmaxf(bf2f(up[j]) + bf2f(vp[j]), 0.f);   // b1 pre-folded into U
            s0 += h * wc[2 * j];
            s1 += h * wc[2 * j + 1];
        }
#pragma unroll
        for (int m = 8; m; m >>= 1) {
            s0 += __shfl_xor(s0, m);
            s1 += __shfl_xor(s1, m);
        }
        if (lane == 0 && ebase + i < nEdges) {
            const int e = ebase + i;
            // softmax over 2 == sigmoid of score difference
            float dlt = (s1 + bb1) - (s0 + bb0);
            float e1 = __expf(dlt);
            float a0 = 1.f / (1.f + e1);
            out[e] = a0;
            out[(size_t)nEdges + e] = 1.f - a0;
        }
    }
}

__global__ __launch_bounds__(256) void detect_only(
    const int* __restrict__ eidx, int nPairs, int* __restrict__ flag)
{
    detect_body(eidx, nPairs, flag);
}

// Last-resort fallback: compute h directly per edge (keeps b1 itself).
__global__ __launch_bounds__(256) void edge_attn_direct(
    const int* __restrict__ eidx, const float* __restrict__ X,
    const float* __restrict__ W1, const float* __restrict__ b1,
    const float* __restrict__ W2, const float* __restrict__ b2,
    const int* __restrict__ i64flag, float* __restrict__ out,
    int nEdges, int nNodes)
{
    const int t = threadIdx.x;
    const int lane = t & 31;
    const int e = blockIdx.x * 8 + (t >> 5);
    if (e >= nEdges) return;
    const int is64 = i64flag ? *i64flag : 0;
    size_t sOff = is64 ? (size_t)2 * e : (size_t)e;
    size_t dOff = is64 ? (size_t)2 * ((size_t)nEdges + e) : (size_t)nEdges + e;
    int si = min(max(eidx[sOff], 0), nNodes - 1);
    int di = min(max(eidx[dOff], 0), nNodes - 1);

    const int j0 = lane * 4;
    float4 bv = *reinterpret_cast<const float4*>(b1 + j0);
    float a0 = bv.x, a1 = bv.y, a2 = bv.z, a3 = bv.w;
    const float* xs = X + (size_t)si * D;
    const float* xd = X + (size_t)di * D;
    for (int k = 0; k < 128; ++k) {
        float s = xs[k];
        float4 w = *reinterpret_cast<const float4*>(W1 + (size_t)k * D + j0);
        a0 += s * w.x; a1 += s * w.y; a2 += s * w.z; a3 += s * w.w;
        float d = xd[k];
        float4 w2r = *reinterpret_cast<const float4*>(W1 + (size_t)(k + 128) * D + j0);
        a0 += d * w2r.x; a1 += d * w2r.y; a2 += d * w2r.z; a3 += d * w2r.w;
    }
    a0 = fmaxf(a0, 0.f); a1 = fmaxf(a1, 0.f); a2 = fmaxf(a2, 0.f); a3 = fmaxf(a3, 0.f);
    float4 wa = *reinterpret_cast<const float4*>(W2 + j0 * 2);
    float4 wb = *reinterpret_cast<const float4*>(W2 + j0 * 2 + 4);
    float s0 = a0 * wa.x + a1 * wa.z + a2 * wb.x + a3 * wb.z;
    float s1 = a0 * wa.y + a1 * wa.w + a2 * wb.y + a3 * wb.w;
#pragma unroll
    for (int m = 16; m; m >>= 1) {
        s0 += __shfl_xor(s0, m);
        s1 += __shfl_xor(s1, m);
    }
    if (lane == 0) {
        s0 += b2[0]; s1 += b2[1];
        float mx = fmaxf(s0, s1);
        float e0 = __expf(s0 - mx), e1 = __expf(s1 - mx);
        float r = 1.f / (e0 + e1);
        out[e] = e0 * r;
        out[(size_t)nEdges + e] = e1 * r;
    }
}

extern "C" void kernel_launch(void* const* d_in, const int* in_sizes, int n_in,
                              void* d_out, int out_size, void* d_ws, size_t ws_size,
                              hipStream_t stream)
{
    const float* X   = (const float*)d_in[0];
    const int*   eix = (const int*)d_in[1];
    const float* W1  = (const float*)d_in[2];
    const float* b1  = (const float*)d_in[3];
    const float* W2  = (const float*)d_in[4];
    const float* b2  = (const float*)d_in[5];
    float* out = (float*)d_out;

    const int nNodes = in_sizes[0] / D;
    const int nEdges = in_sizes[1] / 2;
    const size_t uvElems = (size_t)nNodes * D;
    const size_t uvBytes = uvElems * sizeof(unsigned short);
    const size_t bcBytes = 256 * D * sizeof(unsigned short);   // 64 KB
    const size_t xbBytes = uvElems * sizeof(unsigned short);
    const int nbEdge8 = (nEdges + 127) / 128;

    if (ws_size >= bcBytes + xbBytes + 2 * uvBytes + 16) {
        // tier 1: Bc | Xb | U | V | flag
        unsigned short* Bc = (unsigned short*)d_ws;
        unsigned short* Xb = (unsigned short*)((char*)d_ws + bcBytes);
        unsigned short* U  = (unsigned short*)((char*)d_ws + bcBytes + xbBytes);
        unsigned short* V  = U + uvElems;
        int* flag = (int*)((char*)d_ws + bcBytes + xbBytes + 2 * uvBytes);
        const int nChunks = (int)(uvElems / 8);
        prep<<<129 + (nChunks + 255) / 256, 256, 0, stream>>>(
            X, W1, Bc, Xb, eix, nEdges, flag, nChunks);
        uv_mfma<<<(nNodes + 127) / 128, 256, 0, stream>>>(Xb, Bc, b1, U, V, nNodes);
        edge_attn<<<nbEdge8, 256, 0, stream>>>(eix, U, V, W2, b2, flag, out, nEdges, nNodes);
    } else if (ws_size >= bcBytes + 2 * uvBytes + 16) {
        // tier 2: Bc | U | V | flag
        unsigned short* Bc = (unsigned short*)d_ws;
        unsigned short* U  = (unsigned short*)((char*)d_ws + bcBytes);
        unsigned short* V  = U + uvElems;
        int* flag = (int*)((char*)d_ws + bcBytes + 2 * uvBytes);
        prep<<<129, 256, 0, stream>>>(X, W1, Bc, nullptr, eix, nEdges, flag, 0);
        uv_mfma_f32<<<(nNodes + 63) / 64, 256, 0, stream>>>(X, Bc, b1, U, V, nNodes);
        edge_attn<<<nbEdge8, 256, 0, stream>>>(eix, U, V, W2, b2, flag, out, nEdges, nNodes);
    } else {
        int* flag = (ws_size >= 4) ? (int*)d_ws : nullptr;
        if (flag) detect_only<<<1, 256, 0, stream>>>(eix, nEdges, flag);
        const int nbEdge = (nEdges + 7) / 8;
        edge_attn_direct<<<nbEdge, 256, 0, stream>>>(eix, X, W1, b1, W2, b2, flag, out, nEdges, nNodes);
    }
}